// Round 1
// baseline (128.316 us; speedup 1.0000x reference)
//
#include <hip/hip_runtime.h>

// GraphAttention: B=4, S=512, H=8, DH=64, RD=64, DM=512
// Pipeline:
//  K0  cvt_bf16        : x, Wq, Wk, Wv -> bf16
//  K1  gemm_bf16_nt    : Q/K/V = x @ W^T            (f32 out, M=2048,N=512,K=512, batch=3)
//  K2  postproj        : Qb/Kb (b,h,s,d) bf16; Vt (b,h,d,s) bf16; QR = Q@Wr; qb = Q.br
//  K3  gemm_bf16_nt    : Sqk[b,h,q,k] = Qb @ Kb^T   (batch=32, M=N=512, K=64)
//  K4  rel_mask_softmax: s = (Sqk + QR.rel + qb)/8 + mask; softmax -> P bf16
//      (uses identity q.(rel@Wr^T+br) = (q@Wr).rel + q.br -- rel read ONCE, 256MB)
//  K5  gemm_bf16_nt    : out = P @ Vt^T             (batch=32, M=512, N=64, K=512)

typedef __attribute__((ext_vector_type(4))) float f32x4;
typedef __attribute__((ext_vector_type(8))) short s16x8;
typedef __attribute__((ext_vector_type(4))) unsigned short u16x4;
typedef __attribute__((ext_vector_type(8))) unsigned short u16x8;

__device__ __forceinline__ unsigned short f2bf(float f) {
  union { float f; unsigned int u; } x; x.f = f;
  unsigned int r = (x.u + 0x7fffu + ((x.u >> 16) & 1u)) >> 16;  // RNE
  return (unsigned short)r;
}

__global__ __launch_bounds__(256) void cvt_bf16(const float* __restrict__ src,
                                                unsigned short* __restrict__ dst,
                                                int n) {
  int i = (blockIdx.x * 256 + threadIdx.x) * 4;
  if (i >= n) return;
  f32x4 v = *(const f32x4*)(src + i);
  u16x4 u;
  u.x = f2bf(v.x); u.y = f2bf(v.y); u.z = f2bf(v.z); u.w = f2bf(v.w);
  *(u16x4*)(dst + i) = u;
}

// C[M,N](f32) = A[M,K](bf16,row-major) * B[N,K](bf16,row-major)^T
// 64x64 tile, 4 waves each 32x32 quadrant, K-chunks of 32, mfma 16x16x32.
__global__ __launch_bounds__(256) void gemm_bf16_nt(
    const unsigned short* __restrict__ A, int lda, long sA,
    const unsigned short* __restrict__ Bm, int ldb, long sB,
    float* __restrict__ C, int ldc, int subC, long sC1, long sC2, int K) {
  int z = blockIdx.z;
  A  += (long)z * sA;
  Bm += (long)z * sB;
  C  += (long)(z / subC) * sC1 + (long)(z % subC) * sC2;
  int m0 = blockIdx.x * 64, n0 = blockIdx.y * 64;
  __shared__ alignas(16) unsigned short As[64][40];  // +8 bf16 pad per row
  __shared__ alignas(16) unsigned short Bs[64][40];
  int t = threadIdx.x;
  int lane = t & 63, w = t >> 6;
  int wm = (w >> 1) * 32, wn = (w & 1) * 32;
  int fr = lane & 15, fk = (lane >> 4) * 8;
  int sr = t >> 2, sc = (t & 3) * 8;
  f32x4 acc[2][2] = {};
  for (int k0 = 0; k0 < K; k0 += 32) {
    __syncthreads();
    *(u16x8*)&As[sr][sc] = *(const u16x8*)(A + (long)(m0 + sr) * lda + k0 + sc);
    *(u16x8*)&Bs[sr][sc] = *(const u16x8*)(Bm + (long)(n0 + sr) * ldb + k0 + sc);
    __syncthreads();
    s16x8 a0 = *(const s16x8*)&As[wm + fr][fk];
    s16x8 a1 = *(const s16x8*)&As[wm + 16 + fr][fk];
    s16x8 b0 = *(const s16x8*)&Bs[wn + fr][fk];
    s16x8 b1 = *(const s16x8*)&Bs[wn + 16 + fr][fk];
    acc[0][0] = __builtin_amdgcn_mfma_f32_16x16x32_bf16(a0, b0, acc[0][0], 0, 0, 0);
    acc[0][1] = __builtin_amdgcn_mfma_f32_16x16x32_bf16(a0, b1, acc[0][1], 0, 0, 0);
    acc[1][0] = __builtin_amdgcn_mfma_f32_16x16x32_bf16(a1, b0, acc[1][0], 0, 0, 0);
    acc[1][1] = __builtin_amdgcn_mfma_f32_16x16x32_bf16(a1, b1, acc[1][1], 0, 0, 0);
  }
  int rbase = (lane >> 4) * 4;
#pragma unroll
  for (int i = 0; i < 2; ++i)
#pragma unroll
    for (int j = 0; j < 2; ++j)
#pragma unroll
      for (int jj = 0; jj < 4; ++jj) {
        int row = m0 + wm + 16 * i + rbase + jj;
        int cc  = n0 + wn + 16 * j + fr;
        C[(long)row * ldc + cc] = acc[i][j][jj];
      }
}

// Per (b,s) row: bf16 relayouts + QR = Q@Wr + qb = Q.br
__global__ __launch_bounds__(256) void postproj(
    const float* __restrict__ Qf, const float* __restrict__ Kf,
    const float* __restrict__ Vf, const float* __restrict__ Wr,
    const float* __restrict__ br, unsigned short* __restrict__ Qb,
    unsigned short* __restrict__ Kb, unsigned short* __restrict__ Vt,
    float* __restrict__ QRo, float* __restrict__ qbo) {
  int b = blockIdx.x >> 9, s = blockIdx.x & 511;
  __shared__ float q_lds[512];
  __shared__ float wr_lds[4096];
  __shared__ float br_lds[64];
  int t = threadIdx.x;
  long row = (long)(b * 512 + s) * 512;
#pragma unroll
  for (int i = 0; i < 2; ++i) {
    int e = t + i * 256;
    int h = e >> 6, d = e & 63;
    float qv = Qf[row + e];
    q_lds[e] = qv;
    long hoff = ((long)(b * 8 + h)) * 512;
    Qb[(hoff + s) * 64 + d] = f2bf(qv);
    Kb[(hoff + s) * 64 + d] = f2bf(Kf[row + e]);
    Vt[(((long)(b * 8 + h)) * 64 + d) * 512 + s] = f2bf(Vf[row + e]);
  }
#pragma unroll
  for (int i = 0; i < 16; ++i) { int e = t + i * 256; wr_lds[e] = Wr[e]; }
  if (t < 64) br_lds[t] = br[t];
  __syncthreads();
#pragma unroll
  for (int i = 0; i < 2; ++i) {
    int e = t + i * 256;
    int h = e >> 6, r = e & 63;
    float acc = 0.f;
#pragma unroll 8
    for (int d = 0; d < 64; ++d) acc += q_lds[h * 64 + d] * wr_lds[d * 64 + r];
    QRo[row + e] = acc;  // layout (b,q,h,r) == same flat offset as Q row
  }
  if (t < 8) {
    float a = 0.f;
    for (int d = 0; d < 64; ++d) a += q_lds[t * 64 + d] * br_lds[d];
    qbo[(long)(b * 512 + s) * 8 + t] = a;
  }
}

// Per (b,q): s[h][k] = (Sqk + QR.rel + qb)*0.125 + (1-g)*-1e9 ; softmax over k ; P bf16
__global__ __launch_bounds__(256) void rel_mask_softmax(
    const float* __restrict__ rel, const int* __restrict__ graph,
    const float* __restrict__ Sqk, const float* __restrict__ QR,
    const float* __restrict__ qbv, unsigned short* __restrict__ P) {
  int b = blockIdx.x >> 9, q = blockIdx.x & 511;
  __shared__ float s_lds[8][512];                    // 16KB scores
  __shared__ alignas(16) unsigned short relb[64][72];  // rel chunk bf16 (+pad)
  __shared__ alignas(16) unsigned short qrb[16][72];   // A operand: rows 0..7 QR, 8..15 zero
  __shared__ float qb_lds[8];
  int t = threadIdx.x, lane = t & 63, w = t >> 6;

#pragma unroll
  for (int i = 0; i < 4; ++i) {  // stage Sqk rows (8h x 512)
    int e = i * 1024 + t * 4;
    int h = e >> 9, k = e & 511;
    *(f32x4*)&s_lds[h][k] =
        *(const f32x4*)(Sqk + (((long)(b * 8 + h)) * 512 + q) * 512 + k);
  }
  if (t < 128) {
    int e = t * 4;
    f32x4 v = *(const f32x4*)(QR + ((long)(b * 512 + q)) * 512 + e);
    u16x4 u;
    u.x = f2bf(v.x); u.y = f2bf(v.y); u.z = f2bf(v.z); u.w = f2bf(v.w);
    *(u16x4*)&qrb[e >> 6][e & 63] = u;
  } else {
    int e = (t - 128) * 4;
    u16x4 u = {0, 0, 0, 0};
    *(u16x4*)&qrb[8 + (e >> 6)][e & 63] = u;
  }
  if (t < 8) qb_lds[t] = qbv[((long)(b * 512 + q)) * 8 + t];
  __syncthreads();

  int fr = lane & 15, fk = (lane >> 4) * 8;
  s16x8 aq0 = *(const s16x8*)&qrb[fr][fk];
  s16x8 aq1 = *(const s16x8*)&qrb[fr][32 + fk];
  const float* rg = rel + ((long)(b * 512 + q)) * 512 * 64;

  for (int c = 0; c < 8; ++c) {
    int k0 = c * 64;
    __syncthreads();  // previous chunk's relb reads done
#pragma unroll
    for (int i = 0; i < 4; ++i) {  // stage rel chunk 64k x 64r as bf16
      int e = i * 1024 + t * 4;
      f32x4 v = *(const f32x4*)(rg + (long)k0 * 64 + e);
      u16x4 u;
      u.x = f2bf(v.x); u.y = f2bf(v.y); u.z = f2bf(v.z); u.w = f2bf(v.w);
      *(u16x4*)&relb[e >> 6][e & 63] = u;
    }
    __syncthreads();
    // wave w handles k-subtile [k0+16w, k0+16w+16): C[h][k] = QR[h][:].rel[k][:]
    f32x4 acc = {0.f, 0.f, 0.f, 0.f};
    s16x8 b0 = *(const s16x8*)&relb[16 * w + fr][fk];
    s16x8 b1 = *(const s16x8*)&relb[16 * w + fr][32 + fk];
    acc = __builtin_amdgcn_mfma_f32_16x16x32_bf16(aq0, b0, acc, 0, 0, 0);
    acc = __builtin_amdgcn_mfma_f32_16x16x32_bf16(aq1, b1, acc, 0, 0, 0);
    if (lane < 32) {  // rows(h) 0..7 live in lanes 0..31: row=(lane>>4)*4+j
      int k = k0 + 16 * w + fr;
      int g = graph[((long)(b * 512 + q)) * 512 + k];
      float mask = (1.0f - (float)g) * -1e9f;
      int hb = (lane >> 4) * 4;
#pragma unroll
      for (int j = 0; j < 4; ++j) {
        int h = hb + j;
        s_lds[h][k] = (s_lds[h][k] + acc[j] + qb_lds[h]) * 0.125f + mask;
      }
    }
  }
  __syncthreads();

  for (int h = w; h < 8; h += 4) {  // softmax: wave w does rows w, w+4
    float vals[8];
    float m = -3.0e38f;
#pragma unroll
    for (int i = 0; i < 8; ++i) {
      vals[i] = s_lds[h][lane + 64 * i];
      m = fmaxf(m, vals[i]);
    }
#pragma unroll
    for (int off = 32; off >= 1; off >>= 1) m = fmaxf(m, __shfl_xor(m, off));
    float sum = 0.f;
#pragma unroll
    for (int i = 0; i < 8; ++i) {
      vals[i] = __expf(vals[i] - m);
      sum += vals[i];
    }
#pragma unroll
    for (int off = 32; off >= 1; off >>= 1) sum += __shfl_xor(sum, off);
    float inv = 1.0f / sum;
    unsigned short* Pg = P + (((long)(b * 8 + h)) * 512 + q) * 512;
#pragma unroll
    for (int i = 0; i < 8; ++i) Pg[lane + 64 * i] = f2bf(vals[i] * inv);
  }
}

extern "C" void kernel_launch(void* const* d_in, const int* in_sizes, int n_in,
                              void* d_out, int out_size, void* d_ws, size_t ws_size,
                              hipStream_t stream) {
  const float* x     = (const float*)d_in[0];
  const int*   graph = (const int*)d_in[1];
  const float* rel   = (const float*)d_in[2];
  const float* Wq    = (const float*)d_in[3];
  const float* Wk    = (const float*)d_in[4];
  const float* Wv    = (const float*)d_in[5];
  const float* Wr    = (const float*)d_in[6];
  const float* br    = (const float*)d_in[7];
  float* out = (float*)d_out;

  // workspace carve-up (~73.6 MB total)
  char* wp = (char*)d_ws;
  unsigned short* xb = (unsigned short*)wp; wp += (size_t)2 * 1048576;       // 2MB
  unsigned short* Wb = (unsigned short*)wp; wp += (size_t)2 * 3 * 262144;    // 1.5MB
  float* Qf = (float*)wp;                   wp += (size_t)4 * 3 * 1048576;   // 12MB
  float* Kf = Qf + 1048576;
  float* Vf = Qf + 2 * 1048576;
  unsigned short* Qb = (unsigned short*)wp; wp += (size_t)2 * 1048576;       // 2MB
  unsigned short* Kb = (unsigned short*)wp; wp += (size_t)2 * 1048576;       // 2MB
  unsigned short* Vt = (unsigned short*)wp; wp += (size_t)2 * 1048576;       // 2MB
  float* QR  = (float*)wp;                  wp += (size_t)4 * 1048576;       // 4MB
  float* qbv = (float*)wp;                  wp += (size_t)4 * 16384;         // 64KB
  float* Sqk = (float*)wp;                  wp += (size_t)4 * 8388608;       // 32MB
  unsigned short* P = (unsigned short*)wp;  wp += (size_t)2 * 8388608;       // 16MB

  cvt_bf16<<<1024, 256, 0, stream>>>(x, xb, 1048576);
  cvt_bf16<<<256, 256, 0, stream>>>(Wq, Wb, 262144);
  cvt_bf16<<<256, 256, 0, stream>>>(Wk, Wb + 262144, 262144);
  cvt_bf16<<<256, 256, 0, stream>>>(Wv, Wb + 2 * 262144, 262144);

  // Q/K/V = x @ W^T : M=2048, N=512, K=512, 3 batches over {Wq,Wk,Wv}
  gemm_bf16_nt<<<dim3(32, 8, 3), 256, 0, stream>>>(
      xb, 512, 0L, Wb, 512, 262144L, Qf, 512, 1, 1048576L, 0L, 512);

  postproj<<<2048, 256, 0, stream>>>(Qf, Kf, Vf, Wr, br, Qb, Kb, Vt, QR, qbv);

  // Sqk[b,h] = Qb[b,h] @ Kb[b,h]^T : M=N=512, K=64, 32 batches
  gemm_bf16_nt<<<dim3(8, 8, 32), 256, 0, stream>>>(
      Qb, 64, 32768L, Kb, 64, 32768L, Sqk, 512, 1, 262144L, 0L, 64);

  rel_mask_softmax<<<2048, 256, 0, stream>>>(rel, graph, Sqk, QR, qbv, P);

  // out[b,:,h*64:..] = P[b,h] @ Vt[b,h]^T : M=512, N=64, K=512, 32 batches
  gemm_bf16_nt<<<dim3(8, 1, 32), 256, 0, stream>>>(
      P, 512, 262144L, Vt, 512, 32768L, out, 512, 8, 262144L, 64L, 512);
}

// Round 2
// 104.214 us; speedup vs baseline: 1.2313x; 1.2313x over previous
//
#include <hip/hip_runtime.h>

// GraphAttention: B=4, S=512, H=8, DH=64, RD=64, DM=512
// Pipeline (5 launches):
//  K0 prep      : x->bf16; Wq/Wk/Wv->bf16; Wqr[(h,r),c] = sum_d Wr[d,r]*Wq[h*64+d,c] (bf16)
//  K1 gemm_qkv  : 4 batches of x @ {Wq,Wk,Wv,Wqr}^T, epilogue writes bf16 directly:
//                 Qb/Kb (b,h,s,d), Vt (b,h,d,s), QRb (b,q,h,r)
//  K2 gemm_nt<bf16 out> : Sqkb[b,h,q,k] = Qb @ Kb^T   (batch=32, M=N=512, K=64)
//  K3 rel_fused : s = (Sqk + QR.rel + q.br)/8 + mask; softmax -> P bf16
//                 rel read ONCE (256MB), direct global->register->MFMA, no barriers in loop
//  K4 gemm_nt<f32 out>  : out = P @ Vt^T              (batch=32, M=512, N=64, K=512)

typedef __attribute__((ext_vector_type(4))) float f32x4;
typedef __attribute__((ext_vector_type(8))) short s16x8;
typedef __attribute__((ext_vector_type(4))) unsigned short u16x4;
typedef __attribute__((ext_vector_type(8))) unsigned short u16x8;

__device__ __forceinline__ unsigned short f2bf(float f) {
  union { float f; unsigned int u; } x; x.f = f;
  return (unsigned short)((x.u + 0x7fffu + ((x.u >> 16) & 1u)) >> 16);  // RNE
}
__device__ __forceinline__ float bf2f(unsigned short u) {
  union { unsigned int u; float f; } x; x.u = ((unsigned int)u) << 16;
  return x.f;
}

// grid: 1024 (x cvt) + 768 (W cvt) + 1024 (Wqr) = 2816 blocks x 256
__global__ __launch_bounds__(256) void prep(
    const float* __restrict__ x, const float* __restrict__ Wq,
    const float* __restrict__ Wk, const float* __restrict__ Wv,
    const float* __restrict__ Wr, unsigned short* __restrict__ xb,
    unsigned short* __restrict__ Wb) {
  int blk = blockIdx.x, t = threadIdx.x;
  if (blk < 1024) {
    int i = (blk * 256 + t) * 4;
    f32x4 v = *(const f32x4*)(x + i);
    u16x4 u; u.x = f2bf(v.x); u.y = f2bf(v.y); u.z = f2bf(v.z); u.w = f2bf(v.w);
    *(u16x4*)(xb + i) = u;
  } else if (blk < 1792) {
    int i = ((blk - 1024) * 256 + t) * 4;  // [0, 786432)
    const float* src = (i < 262144) ? Wq : (i < 524288 ? Wk : Wv);
    f32x4 v = *(const f32x4*)(src + (i & 262143));
    u16x4 u; u.x = f2bf(v.x); u.y = f2bf(v.y); u.z = f2bf(v.z); u.w = f2bf(v.w);
    *(u16x4*)(Wb + i) = u;
  } else {
    int o = (blk - 1792) * 256 + t;  // [0, 262144)
    int c = o & 511, n = o >> 9, h = n >> 6, r = n & 63;
    float acc = 0.f;
#pragma unroll 8
    for (int d = 0; d < 64; ++d) acc += Wr[d * 64 + r] * Wq[(h * 64 + d) * 512 + c];
    Wb[3 * 262144 + o] = f2bf(acc);
  }
}

// 64x64 tile, 4 waves, mfma 16x16x32, K=512. Fused relayout epilogues.
__global__ __launch_bounds__(256) void gemm_qkv(
    const unsigned short* __restrict__ xb, const unsigned short* __restrict__ Wb,
    unsigned short* __restrict__ Qb, unsigned short* __restrict__ Kb,
    unsigned short* __restrict__ Vt, unsigned short* __restrict__ QRb) {
  int z = blockIdx.z;
  const unsigned short* A = xb;
  const unsigned short* Bm = Wb + (long)z * 262144;
  int m0 = blockIdx.x * 64, n0 = blockIdx.y * 64;
  __shared__ alignas(16) unsigned short As[64][40];
  __shared__ alignas(16) unsigned short Bs[64][40];
  int t = threadIdx.x, lane = t & 63, w = t >> 6;
  int wm = (w >> 1) * 32, wn = (w & 1) * 32;
  int fr = lane & 15, fk = (lane >> 4) * 8;
  int sr = t >> 2, sc = (t & 3) * 8;
  f32x4 acc[2][2] = {};
  for (int k0 = 0; k0 < 512; k0 += 32) {
    __syncthreads();
    *(u16x8*)&As[sr][sc] = *(const u16x8*)(A + (long)(m0 + sr) * 512 + k0 + sc);
    *(u16x8*)&Bs[sr][sc] = *(const u16x8*)(Bm + (long)(n0 + sr) * 512 + k0 + sc);
    __syncthreads();
    s16x8 a0 = *(const s16x8*)&As[wm + fr][fk];
    s16x8 a1 = *(const s16x8*)&As[wm + 16 + fr][fk];
    s16x8 b0 = *(const s16x8*)&Bs[wn + fr][fk];
    s16x8 b1 = *(const s16x8*)&Bs[wn + 16 + fr][fk];
    acc[0][0] = __builtin_amdgcn_mfma_f32_16x16x32_bf16(a0, b0, acc[0][0], 0, 0, 0);
    acc[0][1] = __builtin_amdgcn_mfma_f32_16x16x32_bf16(a0, b1, acc[0][1], 0, 0, 0);
    acc[1][0] = __builtin_amdgcn_mfma_f32_16x16x32_bf16(a1, b0, acc[1][0], 0, 0, 0);
    acc[1][1] = __builtin_amdgcn_mfma_f32_16x16x32_bf16(a1, b1, acc[1][1], 0, 0, 0);
  }
  int rbase = (lane >> 4) * 4;
#pragma unroll
  for (int i = 0; i < 2; ++i)
#pragma unroll
    for (int j = 0; j < 2; ++j)
#pragma unroll
      for (int jj = 0; jj < 4; ++jj) {
        int row = m0 + wm + 16 * i + rbase + jj;  // m = b*512+s
        int cc  = n0 + wn + 16 * j + fr;          // n = h*64+d  (or h*64+r for QR)
        int b = row >> 9, s = row & 511, h = cc >> 6, d = cc & 63;
        unsigned short val = f2bf(acc[i][j][jj]);
        if (z == 0)      Qb[(((long)(b * 8 + h)) * 512 + s) * 64 + d] = val;
        else if (z == 1) Kb[(((long)(b * 8 + h)) * 512 + s) * 64 + d] = val;
        else if (z == 2) Vt[(((long)(b * 8 + h)) * 64 + d) * 512 + s] = val;
        else             QRb[(long)row * 512 + cc] = val;
      }
}

// Generic NT gemm: C = A @ B^T, bf16 in, f32 or bf16 out.
template <bool OBF16>
__global__ __launch_bounds__(256) void gemm_nt(
    const unsigned short* __restrict__ A, int lda, long sA,
    const unsigned short* __restrict__ Bm, int ldb, long sB,
    void* __restrict__ Cv, int ldc, int subC, long sC1, long sC2, int K) {
  int z = blockIdx.z;
  A  += (long)z * sA;
  Bm += (long)z * sB;
  long coff = (long)(z / subC) * sC1 + (long)(z % subC) * sC2;
  int m0 = blockIdx.x * 64, n0 = blockIdx.y * 64;
  __shared__ alignas(16) unsigned short As[64][40];
  __shared__ alignas(16) unsigned short Bs[64][40];
  int t = threadIdx.x, lane = t & 63, w = t >> 6;
  int wm = (w >> 1) * 32, wn = (w & 1) * 32;
  int fr = lane & 15, fk = (lane >> 4) * 8;
  int sr = t >> 2, sc = (t & 3) * 8;
  f32x4 acc[2][2] = {};
  for (int k0 = 0; k0 < K; k0 += 32) {
    __syncthreads();
    *(u16x8*)&As[sr][sc] = *(const u16x8*)(A + (long)(m0 + sr) * lda + k0 + sc);
    *(u16x8*)&Bs[sr][sc] = *(const u16x8*)(Bm + (long)(n0 + sr) * ldb + k0 + sc);
    __syncthreads();
    s16x8 a0 = *(const s16x8*)&As[wm + fr][fk];
    s16x8 a1 = *(const s16x8*)&As[wm + 16 + fr][fk];
    s16x8 b0 = *(const s16x8*)&Bs[wn + fr][fk];
    s16x8 b1 = *(const s16x8*)&Bs[wn + 16 + fr][fk];
    acc[0][0] = __builtin_amdgcn_mfma_f32_16x16x32_bf16(a0, b0, acc[0][0], 0, 0, 0);
    acc[0][1] = __builtin_amdgcn_mfma_f32_16x16x32_bf16(a0, b1, acc[0][1], 0, 0, 0);
    acc[1][0] = __builtin_amdgcn_mfma_f32_16x16x32_bf16(a1, b0, acc[1][0], 0, 0, 0);
    acc[1][1] = __builtin_amdgcn_mfma_f32_16x16x32_bf16(a1, b1, acc[1][1], 0, 0, 0);
  }
  int rbase = (lane >> 4) * 4;
#pragma unroll
  for (int i = 0; i < 2; ++i)
#pragma unroll
    for (int j = 0; j < 2; ++j)
#pragma unroll
      for (int jj = 0; jj < 4; ++jj) {
        long row = m0 + wm + 16 * i + rbase + jj;
        int cc   = n0 + wn + 16 * j + fr;
        if (OBF16)
          ((unsigned short*)Cv)[coff + row * ldc + cc] = f2bf(acc[i][j][jj]);
        else
          ((float*)Cv)[coff + row * ldc + cc] = acc[i][j][jj];
      }
}

// Per (b,q): s[h][k] = (Sqk + QR.rel + qb)*0.125 + mask ; softmax ; P bf16.
// rel read direct global->reg->bf16 frag; each k written once; no loop barriers.
__global__ __launch_bounds__(256) void rel_fused(
    const float* __restrict__ rel, const int* __restrict__ graph,
    const unsigned short* __restrict__ Sqkb, const unsigned short* __restrict__ QRb,
    const unsigned short* __restrict__ Qb, const float* __restrict__ br,
    unsigned short* __restrict__ P) {
  int b = blockIdx.x >> 9, q = blockIdx.x & 511;
  __shared__ float s_lds[8][512];            // 16KB: rel-term scores
  __shared__ unsigned short qr16[16][64];    // A operand: rows 0..7 = QR, 8..15 = 0
  __shared__ float qb_lds[8];
  int t = threadIdx.x, lane = t & 63, w = t >> 6;

  if (t < 64) {
    u16x8 v = *(const u16x8*)(QRb + ((long)(b * 512 + q)) * 512 + t * 8);
    *(u16x8*)&qr16[t >> 3][(t & 7) * 8] = v;
  } else if (t < 128) {
    u16x8 zv = {};
    *(u16x8*)&qr16[8 + ((t - 64) >> 3)][((t - 64) & 7) * 8] = zv;
  }
  if (t >= 128 && t < 136) {
    int h = t - 128;
    const unsigned short* qrow = Qb + (((long)(b * 8 + h)) * 512 + q) * 64;
    float a = 0.f;
#pragma unroll 16
    for (int d = 0; d < 64; ++d) a += bf2f(qrow[d]) * br[d];
    qb_lds[h] = a;
  }
  __syncthreads();

  int fr = lane & 15, fk = (lane >> 4) * 8;
  s16x8 aq0 = *(const s16x8*)&qr16[fr][fk];
  s16x8 aq1 = *(const s16x8*)&qr16[fr][32 + fk];
  const float* rg = rel + ((long)(b * 512 + q)) * 32768;

  for (int c = 0; c < 8; ++c) {
    int krow = c * 64 + 16 * w + fr;
    const float* rp = rg + krow * 64;
    f32x4 r0 = *(const f32x4*)(rp + fk);
    f32x4 r1 = *(const f32x4*)(rp + fk + 4);
    f32x4 r2 = *(const f32x4*)(rp + 32 + fk);
    f32x4 r3 = *(const f32x4*)(rp + 32 + fk + 4);
    s16x8 b0, b1;
    b0[0] = (short)f2bf(r0.x); b0[1] = (short)f2bf(r0.y);
    b0[2] = (short)f2bf(r0.z); b0[3] = (short)f2bf(r0.w);
    b0[4] = (short)f2bf(r1.x); b0[5] = (short)f2bf(r1.y);
    b0[6] = (short)f2bf(r1.z); b0[7] = (short)f2bf(r1.w);
    b1[0] = (short)f2bf(r2.x); b1[1] = (short)f2bf(r2.y);
    b1[2] = (short)f2bf(r2.z); b1[3] = (short)f2bf(r2.w);
    b1[4] = (short)f2bf(r3.x); b1[5] = (short)f2bf(r3.y);
    b1[6] = (short)f2bf(r3.z); b1[7] = (short)f2bf(r3.w);
    f32x4 acc = {};
    acc = __builtin_amdgcn_mfma_f32_16x16x32_bf16(aq0, b0, acc, 0, 0, 0);
    acc = __builtin_amdgcn_mfma_f32_16x16x32_bf16(aq1, b1, acc, 0, 0, 0);
    if (lane < 32) {  // rows(h) 0..7: row=(lane>>4)*4+j, col k = own loaded row
      int k = c * 64 + 16 * w + fr;
      int hb = (lane >> 4) * 4;
#pragma unroll
      for (int j = 0; j < 4; ++j) s_lds[hb + j][k] = acc[j];
    }
  }
  __syncthreads();

  const int* grow = graph + ((long)(b * 512 + q)) * 512;
  for (int h = w; h < 8; h += 4) {  // wave w: rows h = w, w+4
    const unsigned short* srow = Sqkb + (((long)(b * 8 + h)) * 512 + q) * 512;
    float qbh = qb_lds[h];
    float vals[8];
    float m = -3.0e38f;
#pragma unroll
    for (int i = 0; i < 8; ++i) {
      int k = lane + 64 * i;
      float msk = (1.0f - (float)grow[k]) * -1e9f;
      vals[i] = (s_lds[h][k] + bf2f(srow[k]) + qbh) * 0.125f + msk;
      m = fmaxf(m, vals[i]);
    }
#pragma unroll
    for (int off = 32; off >= 1; off >>= 1) m = fmaxf(m, __shfl_xor(m, off));
    float sum = 0.f;
#pragma unroll
    for (int i = 0; i < 8; ++i) { vals[i] = __expf(vals[i] - m); sum += vals[i]; }
#pragma unroll
    for (int off = 32; off >= 1; off >>= 1) sum += __shfl_xor(sum, off);
    float inv = 1.0f / sum;
    unsigned short* Pg = P + (((long)(b * 8 + h)) * 512 + q) * 512;
#pragma unroll
    for (int i = 0; i < 8; ++i) Pg[lane + 64 * i] = f2bf(vals[i] * inv);
  }
}

extern "C" void kernel_launch(void* const* d_in, const int* in_sizes, int n_in,
                              void* d_out, int out_size, void* d_ws, size_t ws_size,
                              hipStream_t stream) {
  const float* x     = (const float*)d_in[0];
  const int*   graph = (const int*)d_in[1];
  const float* rel   = (const float*)d_in[2];
  const float* Wq    = (const float*)d_in[3];
  const float* Wk    = (const float*)d_in[4];
  const float* Wv    = (const float*)d_in[5];
  const float* Wr    = (const float*)d_in[6];
  const float* br    = (const float*)d_in[7];
  float* out = (float*)d_out;

  // workspace (~44MB)
  char* wp = (char*)d_ws;
  unsigned short* xb  = (unsigned short*)wp; wp += (size_t)2 * 1048576;      // 2MB
  unsigned short* Wb  = (unsigned short*)wp; wp += (size_t)2 * 4 * 262144;   // 2MB (Wq,Wk,Wv,Wqr)
  unsigned short* Qb  = (unsigned short*)wp; wp += (size_t)2 * 1048576;      // 2MB
  unsigned short* Kb  = (unsigned short*)wp; wp += (size_t)2 * 1048576;      // 2MB
  unsigned short* Vt  = (unsigned short*)wp; wp += (size_t)2 * 1048576;      // 2MB
  unsigned short* QRb = (unsigned short*)wp; wp += (size_t)2 * 1048576;      // 2MB
  unsigned short* Sqkb = (unsigned short*)wp; wp += (size_t)2 * 8388608;     // 16MB
  unsigned short* P   = (unsigned short*)wp; wp += (size_t)2 * 8388608;      // 16MB

  prep<<<2816, 256, 0, stream>>>(x, Wq, Wk, Wv, Wr, xb, Wb);

  // Q/K/V/QR: M=2048, N=512, K=512, 4 batches, fused bf16 relayout epilogue
  gemm_qkv<<<dim3(32, 8, 4), 256, 0, stream>>>(xb, Wb, Qb, Kb, Vt, QRb);

  // Sqk[b,h] = Qb @ Kb^T : M=N=512, K=64, 32 batches, bf16 out
  gemm_nt<true><<<dim3(8, 8, 32), 256, 0, stream>>>(
      Qb, 64, 32768L, Kb, 64, 32768L, Sqkb, 512, 1, 262144L, 0L, 64);

  rel_fused<<<2048, 256, 0, stream>>>(rel, graph, Sqkb, QRb, Qb, br, P);

  // out[b,:,h*64+d] = P[b,h] @ Vt[b,h]^T : M=512, N=64, K=512, 32 batches, f32 out
  gemm_nt<false><<<dim3(8, 1, 32), 256, 0, stream>>>(
      P, 512, 262144L, Vt, 512, 32768L, out, 512, 8, 262144L, 64L, 512);
}